// Round 2
// baseline (2174.228 us; speedup 1.0000x reference)
//
#include <hip/hip_runtime.h>
#include <hip/hip_bf16.h>

// ---------------------------------------------------------------------------
// MCT tracklet-affinity pipeline. fp32 in/out (per reference dtypes), bf16
// MFMA internally:
//   g   = f - relu(f @ Wc1^T + bc1)              [192,4096]  fp32 in ws
//   h1  = relu(|g_i - g_j| @ W1^T + b1)          [36864,2048] bf16 (chunked)
//   h2  = relu(h1 @ W2^T + b2)                   [.,1024]
//   h3  = relu(h2 @ W3^T + b3)                   [.,512]
//   A   = sigmoid(h3 @ Ws^T + bs)                [192,192] fp32
// Weights pre-converted fp32->bf16 once into ws so all GEMMs use the m97
// global_load_lds width-16 staging. dist rows generated on the fly from fp32
// g (never materializes the 604MB fp32 dist tensor). 16x16x32 bf16 MFMA,
// fp32 accum, C/D mapping row=(lane>>4)*4+reg, col=lane&15 (m89/m91).
// ---------------------------------------------------------------------------

typedef unsigned short u16;
typedef __attribute__((ext_vector_type(8))) short    bf16x8;  // 8 bf16 = 4 VGPR
typedef __attribute__((ext_vector_type(8))) unsigned short u16x8;
typedef __attribute__((ext_vector_type(4))) float    f32x4;

#define MFMA16(a, b, c) __builtin_amdgcn_mfma_f32_16x16x32_bf16((a), (b), (c), 0, 0, 0)

__device__ __forceinline__ unsigned int pkbf(float lo, float hi) {
    __hip_bfloat162 h2 = __float22bfloat162_rn(make_float2(lo, hi));
    return *reinterpret_cast<unsigned int*>(&h2);
}
// async global->LDS, 16B per lane; lds dst is wave-uniform base (HW adds lane*16)
__device__ __forceinline__ void gll16(void* lds_uniform, const void* gsrc) {
    __builtin_amdgcn_global_load_lds(
        (__attribute__((address_space(1))) void*)(gsrc),
        (__attribute__((address_space(3))) void*)(lds_uniform),
        16, 0, 0);
}

// ---------------------------------------------------------------------------
// fp32 -> bf16 elementwise (n4 = count/4)
// ---------------------------------------------------------------------------
__global__ __launch_bounds__(256)
void k_cvt(const float* __restrict__ src, u16* __restrict__ dst, int n4)
{
    int i = blockIdx.x * blockDim.x + threadIdx.x;
    const int stride = gridDim.x * blockDim.x;
    for (; i < n4; i += stride) {
        f32x4 v = ((const f32x4*)src)[i];
        ((uint2*)dst)[i] = make_uint2(pkbf(v.x, v.y), pkbf(v.z, v.w));
    }
}

// ---------------------------------------------------------------------------
// Kernel 1: g = f - relu(fb @ Wc1b^T + bc1).  M=192,N=4096,K=4096.
// BM=64, BN=128, BK=64. 256 thr (4 waves, 2x2), wave tile 32x64. grid (3,32).
// ---------------------------------------------------------------------------
__global__ __launch_bounds__(256, 2)
void k_cam(const u16* __restrict__ fb, const u16* __restrict__ Wc1b,
           const float* __restrict__ bc1, const float* __restrict__ f,
           float* __restrict__ gout)
{
    __shared__ __align__(16) u16 As[64 * 64];
    __shared__ __align__(16) u16 Bs[128 * 64];
    const int t = threadIdx.x, l = t & 63, w = t >> 6;
    const int m0 = blockIdx.x * 64, n0 = blockIdx.y * 128;
    const u16* Ab = fb   + (size_t)(m0 + w * 16 + (l >> 3)) * 4096 + (l & 7) * 8;
    const u16* Bb = Wc1b + (size_t)(n0 + w * 32 + (l >> 3)) * 4096 + (l & 7) * 8;
    f32x4 acc[2][4] = {};
    const int wr = (w >> 1) * 32, wc = (w & 1) * 64;
    const int lrow = l & 15, lk = (l >> 4) * 8;

    for (int k0 = 0; k0 < 4096; k0 += 64) {
        __syncthreads();
#pragma unroll
        for (int q = 0; q < 2; ++q)
            gll16(&As[(w * 16 + q * 8) * 64], Ab + (size_t)q * 8 * 4096 + k0);
#pragma unroll
        for (int q = 0; q < 4; ++q)
            gll16(&Bs[(w * 32 + q * 8) * 64], Bb + (size_t)q * 8 * 4096 + k0);
        __syncthreads();
#pragma unroll
        for (int kk = 0; kk < 64; kk += 32) {
            bf16x8 af[2], bfr[4];
#pragma unroll
            for (int mi = 0; mi < 2; ++mi)
                af[mi] = *(const bf16x8*)&As[(wr + mi * 16 + lrow) * 64 + kk + lk];
#pragma unroll
            for (int ni = 0; ni < 4; ++ni)
                bfr[ni] = *(const bf16x8*)&Bs[(wc + ni * 16 + lrow) * 64 + kk + lk];
#pragma unroll
            for (int mi = 0; mi < 2; ++mi)
#pragma unroll
                for (int ni = 0; ni < 4; ++ni)
                    acc[mi][ni] = MFMA16(af[mi], bfr[ni], acc[mi][ni]);
        }
    }
    const int rq = (l >> 4) * 4;
#pragma unroll
    for (int ni = 0; ni < 4; ++ni) {
        const int col = n0 + wc + ni * 16 + lrow;
        const float bias = bc1[col];
#pragma unroll
        for (int mi = 0; mi < 2; ++mi) {
            const int rbase = m0 + wr + mi * 16 + rq;
#pragma unroll
            for (int v = 0; v < 4; ++v) {
                const int row = rbase + v;
                float cam = fmaxf(acc[mi][ni][v] + bias, 0.0f);
                gout[(size_t)row * 4096 + col] = f[(size_t)row * 4096 + col] - cam;
            }
        }
    }
}

// ---------------------------------------------------------------------------
// Kernel 2: h1 = relu(dist @ W1b^T + b1), dist rows generated from fp32 g.
// BM=128, BN=256, BK=64. 256 thr (4 waves, 2x2), wave tile 64x128.
// As padded to LD=72 u16 (144B = 4-bank rotation/row) to kill the 32-way
// bank conflict of the per-thread b128 dist stores. grid (R/128, 8).
// ---------------------------------------------------------------------------
#define ALD 72
__global__ __launch_bounds__(256, 2)
void k_dist_l1(const float* __restrict__ g, const u16* __restrict__ W1b,
               const float* __restrict__ b1, u16* __restrict__ h1, int row0)
{
    __shared__ __align__(16) u16 As[128 * ALD];  // 18 KB dist tile (padded)
    __shared__ __align__(16) u16 Bs[256 * 64];   // 32 KB W1 tile
    const int t = threadIdx.x, l = t & 63, w = t >> 6;
    const int mloc0 = blockIdx.x * 128;
    const int n0 = blockIdx.y * 256;

    // per-thread dist staging: row (t>>1), 32 k's at (t&1)*32
    const int srow = t >> 1;
    const int skof = (t & 1) * 32;
    const int rg = row0 + mloc0 + srow;          // global pair index
    const int pi = rg / 192;
    const int pj = rg - pi * 192;
    const float* gi = g + (size_t)pi * 4096 + skof;
    const float* gj = g + (size_t)pj * 4096 + skof;
    u16* As_dst = &As[srow * ALD + skof];

    const u16* Wb = W1b + (size_t)(n0 + w * 64 + (l >> 3)) * 4096 + (l & 7) * 8;

    f32x4 acc[4][8] = {};
    const int wr = (w >> 1) * 64, wc = (w & 1) * 128;
    const int lrow = l & 15, lk = (l >> 4) * 8;

    for (int k0 = 0; k0 < 4096; k0 += 64) {
        __syncthreads();
        // B: async global->LDS (8 insts/wave, 8 rows each => 64 rows/wave)
#pragma unroll
        for (int q = 0; q < 8; ++q)
            gll16(&Bs[(w * 64 + q * 8) * 64], Wb + (size_t)q * 8 * 4096 + k0);
        // A: |g_i - g_j| for this thread's 32 elements, packed bf16 -> LDS
#pragma unroll
        for (int u2 = 0; u2 < 4; ++u2) {
            const float* aj = gj + k0 + u2 * 8;
            const float* ai = gi + k0 + u2 * 8;
            f32x4 j0 = *(const f32x4*)(aj);
            f32x4 j1 = *(const f32x4*)(aj + 4);
            f32x4 i0 = *(const f32x4*)(ai);
            f32x4 i1 = *(const f32x4*)(ai + 4);
            unsigned int p0 = pkbf(fabsf(j0.x - i0.x), fabsf(j0.y - i0.y));
            unsigned int p1 = pkbf(fabsf(j0.z - i0.z), fabsf(j0.w - i0.w));
            unsigned int p2 = pkbf(fabsf(j1.x - i1.x), fabsf(j1.y - i1.y));
            unsigned int p3 = pkbf(fabsf(j1.z - i1.z), fabsf(j1.w - i1.w));
            *reinterpret_cast<uint4*>(As_dst + u2 * 8) = make_uint4(p0, p1, p2, p3);
        }
        __syncthreads();
#pragma unroll
        for (int kk = 0; kk < 64; kk += 32) {
            bf16x8 af[4], bfr[8];
#pragma unroll
            for (int mi = 0; mi < 4; ++mi)
                af[mi] = *(const bf16x8*)&As[(wr + mi * 16 + lrow) * ALD + kk + lk];
#pragma unroll
            for (int ni = 0; ni < 8; ++ni)
                bfr[ni] = *(const bf16x8*)&Bs[(wc + ni * 16 + lrow) * 64 + kk + lk];
#pragma unroll
            for (int mi = 0; mi < 4; ++mi)
#pragma unroll
                for (int ni = 0; ni < 8; ++ni)
                    acc[mi][ni] = MFMA16(af[mi], bfr[ni], acc[mi][ni]);
        }
    }
    const int rq = (l >> 4) * 4;
#pragma unroll
    for (int ni = 0; ni < 8; ++ni) {
        const int col = n0 + wc + ni * 16 + lrow;
        const float bias = b1[col];
#pragma unroll
        for (int mi = 0; mi < 4; ++mi) {
            const int rbase = mloc0 + wr + mi * 16 + rq;
#pragma unroll
            for (int v = 0; v < 4; ++v) {
                float x = fmaxf(acc[mi][ni][v] + bias, 0.0f);
                unsigned int ub = pkbf(x, 0.0f);
                h1[(size_t)(rbase + v) * 2048 + col] = (u16)(ub & 0xFFFF);
            }
        }
    }
}

// ---------------------------------------------------------------------------
// Kernel 3: generic C = relu(A @ B^T + bias), bf16 A/B/C, fp32 bias.
// BM=BN=128, BK=64. 256 thr, wave tile 64x64. grid (M/128, N/128).
// ---------------------------------------------------------------------------
__global__ __launch_bounds__(256, 2)
void k_gemm_relu(const u16* __restrict__ A, const u16* __restrict__ B,
                 const float* __restrict__ bias, u16* __restrict__ C,
                 int N, int K)
{
    __shared__ __align__(16) u16 As[128 * 64];
    __shared__ __align__(16) u16 Bs[128 * 64];
    const int t = threadIdx.x, l = t & 63, w = t >> 6;
    const int m0 = blockIdx.x * 128, n0 = blockIdx.y * 128;
    const u16* Ab = A + (size_t)(m0 + w * 32 + (l >> 3)) * K + (l & 7) * 8;
    const u16* Bb = B + (size_t)(n0 + w * 32 + (l >> 3)) * K + (l & 7) * 8;
    f32x4 acc[4][4] = {};
    const int wr = (w >> 1) * 64, wc = (w & 1) * 64;
    const int lrow = l & 15, lk = (l >> 4) * 8;

    for (int k0 = 0; k0 < K; k0 += 64) {
        __syncthreads();
#pragma unroll
        for (int q = 0; q < 4; ++q) {
            gll16(&As[(w * 32 + q * 8) * 64], Ab + (size_t)q * 8 * K + k0);
            gll16(&Bs[(w * 32 + q * 8) * 64], Bb + (size_t)q * 8 * K + k0);
        }
        __syncthreads();
#pragma unroll
        for (int kk = 0; kk < 64; kk += 32) {
            bf16x8 af[4], bfr[4];
#pragma unroll
            for (int mi = 0; mi < 4; ++mi)
                af[mi] = *(const bf16x8*)&As[(wr + mi * 16 + lrow) * 64 + kk + lk];
#pragma unroll
            for (int ni = 0; ni < 4; ++ni)
                bfr[ni] = *(const bf16x8*)&Bs[(wc + ni * 16 + lrow) * 64 + kk + lk];
#pragma unroll
            for (int mi = 0; mi < 4; ++mi)
#pragma unroll
                for (int ni = 0; ni < 4; ++ni)
                    acc[mi][ni] = MFMA16(af[mi], bfr[ni], acc[mi][ni]);
        }
    }
    const int rq = (l >> 4) * 4;
#pragma unroll
    for (int ni = 0; ni < 4; ++ni) {
        const int col = n0 + wc + ni * 16 + lrow;
        const float bv = bias[col];
#pragma unroll
        for (int mi = 0; mi < 4; ++mi) {
            const int rbase = m0 + wr + mi * 16 + rq;
#pragma unroll
            for (int v = 0; v < 4; ++v) {
                float x = fmaxf(acc[mi][ni][v] + bv, 0.0f);
                unsigned int ub = pkbf(x, 0.0f);
                C[(size_t)(rbase + v) * N + col] = (u16)(ub & 0xFFFF);
            }
        }
    }
}

// ---------------------------------------------------------------------------
// Kernel 4: out[r] = sigmoid(h3[r,:512] . Ws + bs). One wave per row.
// ---------------------------------------------------------------------------
__global__ __launch_bounds__(256)
void k_head(const u16* __restrict__ h3, const float* __restrict__ Wsv,
            const float* __restrict__ bsv, float* __restrict__ out, int row0)
{
    const int t = threadIdx.x, l = t & 63, wv = t >> 6;
    const int r = blockIdx.x * 4 + wv;
    const u16x8 hv = *(const u16x8*)(h3 + (size_t)r * 512 + l * 8);
    const f32x4 w0 = ((const f32x4*)Wsv)[l * 2];
    const f32x4 w1 = ((const f32x4*)Wsv)[l * 2 + 1];
    float hs[8];
#pragma unroll
    for (int e = 0; e < 8; ++e) {
        union { unsigned int i; float f; } v;
        v.i = ((unsigned int)hv[e]) << 16;
        hs[e] = v.f;
    }
    float s = hs[0] * w0.x + hs[1] * w0.y + hs[2] * w0.z + hs[3] * w0.w
            + hs[4] * w1.x + hs[5] * w1.y + hs[6] * w1.z + hs[7] * w1.w;
#pragma unroll
    for (int off = 32; off >= 1; off >>= 1) s += __shfl_down(s, off, 64);
    if (l == 0) {
        float logit = s + bsv[0];
        out[row0 + r] = 1.0f / (1.0f + __expf(-logit));
    }
}

// ---------------------------------------------------------------------------
extern "C" void kernel_launch(void* const* d_in, const int* in_sizes, int n_in,
                              void* d_out, int out_size, void* d_ws, size_t ws_size,
                              hipStream_t stream)
{
    const float* f   = (const float*)d_in[0];
    const float* Wc1 = (const float*)d_in[1];
    const float* bc1 = (const float*)d_in[2];
    const float* W1  = (const float*)d_in[3];
    const float* b1  = (const float*)d_in[4];
    const float* W2  = (const float*)d_in[5];
    const float* b2  = (const float*)d_in[6];
    const float* W3  = (const float*)d_in[7];
    const float* b3  = (const float*)d_in[8];
    const float* Wsv = (const float*)d_in[9];
    const float* bsv = (const float*)d_in[10];
    float* out = (float*)d_out;

    // ---- workspace layout (bytes) ----
    char* wsb = (char*)d_ws;
    size_t off = 0;
    u16* Wc1b = (u16*)(wsb + off); off += (size_t)4096 * 4096 * 2;  // 32 MB
    u16* W1b  = (u16*)(wsb + off); off += (size_t)2048 * 4096 * 2;  // 16 MB
    u16* W2b  = (u16*)(wsb + off); off += (size_t)1024 * 2048 * 2;  //  4 MB
    u16* W3b  = (u16*)(wsb + off); off += (size_t)512  * 1024 * 2;  //  1 MB
    u16* fb   = (u16*)(wsb + off); off += (size_t)192  * 4096 * 2;  // 1.5 MB
    float* g  = (float*)(wsb + off); off += (size_t)192 * 4096 * 4; //  3 MB
    const size_t fixed = off;

    // chunk size: CI source-tracklets -> R = CI*192 pair-rows (R % 128 == 0)
    const int CIs[5] = {48, 24, 12, 6, 2};
    int CI = 2;
    for (int c = 0; c < 5; ++c) {
        size_t need = fixed + (size_t)CIs[c] * 192 * (2048 + 1024 + 512) * 2;
        if (need <= ws_size) { CI = CIs[c]; break; }
    }
    const int R = CI * 192;
    u16* h1 = (u16*)(wsb + fixed);
    u16* h2 = h1 + (size_t)R * 2048;
    u16* h3 = h2 + (size_t)R * 1024;

    // ---- weight/input fp32 -> bf16 conversion ----
    k_cvt<<<512, 256, 0, stream>>>(Wc1, Wc1b, 4096 * 4096 / 4);
    k_cvt<<<512, 256, 0, stream>>>(W1,  W1b,  2048 * 4096 / 4);
    k_cvt<<<256, 256, 0, stream>>>(W2,  W2b,  1024 * 2048 / 4);
    k_cvt<<<128, 256, 0, stream>>>(W3,  W3b,  512  * 1024 / 4);
    k_cvt<<<128, 256, 0, stream>>>(f,   fb,   192  * 4096 / 4);

    k_cam<<<dim3(3, 32), 256, 0, stream>>>(fb, Wc1b, bc1, f, g);
    for (int r0 = 0; r0 < 36864; r0 += R) {
        k_dist_l1<<<dim3(R / 128, 8), 256, 0, stream>>>(g, W1b, b1, h1, r0);
        k_gemm_relu<<<dim3(R / 128, 8), 256, 0, stream>>>(h1, W2b, b2, h2, 1024, 2048);
        k_gemm_relu<<<dim3(R / 128, 4), 256, 0, stream>>>(h2, W3b, b3, h3, 512, 1024);
        k_head<<<dim3(R / 4), 256, 0, stream>>>(h3, Wsv, bsv, out, r0);
    }
}

// Round 3
// 876.131 us; speedup vs baseline: 2.4816x; 2.4816x over previous
//
#include <hip/hip_runtime.h>
#include <hip/hip_bf16.h>

// ---------------------------------------------------------------------------
// MCT tracklet-affinity pipeline. fp32 in/out, bf16 MFMA internally.
//   g   = f - relu(f @ Wc1^T + bc1)              [192,4096] fp32 in ws
//   dist rows: ONLY upper triangle (i<=j), 18528 rows (A is symmetric)
//   h1  = relu(|g_i - g_j| @ W1^T + b1)          [T,2048] bf16
//   h2  = relu(h1 @ W2^T + b2)                   [T,1024]
//   h3  = relu(h2 @ W3^T + b3)                   [T,512]
//   A[i,j] = A[j,i] = sigmoid(h3 . Ws + bs)      [192,192] fp32
// A-staging coalesced: 8 lanes/row, 16B chunks; per-thread row ptrs decoded
// once in prologue. 16x16x32 bf16 MFMA, C/D row=(lane>>4)*4+reg, col=lane&15.
// ---------------------------------------------------------------------------

typedef unsigned short u16;
typedef __attribute__((ext_vector_type(8))) short    bf16x8;
typedef __attribute__((ext_vector_type(8))) unsigned short u16x8;
typedef __attribute__((ext_vector_type(4))) float    f32x4;

#define MFMA16(a, b, c) __builtin_amdgcn_mfma_f32_16x16x32_bf16((a), (b), (c), 0, 0, 0)

#define NTRK 192
#define TRI  18528         /* 192*193/2 upper-tri rows incl diagonal */
#define TRIP 18688         /* padded to 146*128 */

__device__ __forceinline__ unsigned int pkbf(float lo, float hi) {
    __hip_bfloat162 h2 = __float22bfloat162_rn(make_float2(lo, hi));
    return *reinterpret_cast<unsigned int*>(&h2);
}
__device__ __forceinline__ void gll16(void* lds_uniform, const void* gsrc) {
    __builtin_amdgcn_global_load_lds(
        (__attribute__((address_space(1))) void*)(gsrc),
        (__attribute__((address_space(3))) void*)(lds_uniform),
        16, 0, 0);
}
// triangle row r -> (i,j), i<=j. T(i) = i*(385-i)/2. Clamped for padding rows.
__device__ __forceinline__ void tri_decode(int r, int& oi, int& oj) {
    double a = 192.5;
    int i = (int)(a - sqrt(a * a - 2.0 * (double)r));
    i = i < 0 ? 0 : (i > 191 ? 191 : i);
    while (i < 191 && (i + 1) * (385 - (i + 1)) / 2 <= r) ++i;
    while (i > 0 && i * (385 - i) / 2 > r) --i;
    int j = i + (r - i * (385 - i) / 2);
    oi = i; oj = j > 191 ? 191 : j;
}

// ---------------------------------------------------------------------------
__global__ __launch_bounds__(256)
void k_cvt(const float* __restrict__ src, u16* __restrict__ dst, int n4)
{
    int i = blockIdx.x * blockDim.x + threadIdx.x;
    const int stride = gridDim.x * blockDim.x;
    for (; i < n4; i += stride) {
        f32x4 v = ((const f32x4*)src)[i];
        ((uint2*)dst)[i] = make_uint2(pkbf(v.x, v.y), pkbf(v.z, v.w));
    }
}

// ---------------------------------------------------------------------------
// g = f - relu(fb @ Wc1b^T + bc1).  M=192,N=4096,K=4096. BM=64,BN=128,BK=64.
// ---------------------------------------------------------------------------
__global__ __launch_bounds__(256, 2)
void k_cam(const u16* __restrict__ fb, const u16* __restrict__ Wc1b,
           const float* __restrict__ bc1, const float* __restrict__ f,
           float* __restrict__ gout)
{
    __shared__ __align__(16) u16 As[64 * 64];
    __shared__ __align__(16) u16 Bs[128 * 64];
    const int t = threadIdx.x, l = t & 63, w = t >> 6;
    const int m0 = blockIdx.x * 64, n0 = blockIdx.y * 128;
    const u16* Ab = fb   + (size_t)(m0 + w * 16 + (l >> 3)) * 4096 + (l & 7) * 8;
    const u16* Bb = Wc1b + (size_t)(n0 + w * 32 + (l >> 3)) * 4096 + (l & 7) * 8;
    f32x4 acc[2][4] = {};
    const int wr = (w >> 1) * 32, wc = (w & 1) * 64;
    const int lrow = l & 15, lk = (l >> 4) * 8;

    for (int k0 = 0; k0 < 4096; k0 += 64) {
        __syncthreads();
#pragma unroll
        for (int q = 0; q < 2; ++q)
            gll16(&As[(w * 16 + q * 8) * 64], Ab + (size_t)q * 8 * 4096 + k0);
#pragma unroll
        for (int q = 0; q < 4; ++q)
            gll16(&Bs[(w * 32 + q * 8) * 64], Bb + (size_t)q * 8 * 4096 + k0);
        __syncthreads();
#pragma unroll
        for (int kk = 0; kk < 64; kk += 32) {
            bf16x8 af[2], bfr[4];
#pragma unroll
            for (int mi = 0; mi < 2; ++mi)
                af[mi] = *(const bf16x8*)&As[(wr + mi * 16 + lrow) * 64 + kk + lk];
#pragma unroll
            for (int ni = 0; ni < 4; ++ni)
                bfr[ni] = *(const bf16x8*)&Bs[(wc + ni * 16 + lrow) * 64 + kk + lk];
#pragma unroll
            for (int mi = 0; mi < 2; ++mi)
#pragma unroll
                for (int ni = 0; ni < 4; ++ni)
                    acc[mi][ni] = MFMA16(af[mi], bfr[ni], acc[mi][ni]);
        }
    }
    const int rq = (l >> 4) * 4;
#pragma unroll
    for (int ni = 0; ni < 4; ++ni) {
        const int col = n0 + wc + ni * 16 + lrow;
        const float bias = bc1[col];
#pragma unroll
        for (int mi = 0; mi < 2; ++mi) {
            const int rbase = m0 + wr + mi * 16 + rq;
#pragma unroll
            for (int v = 0; v < 4; ++v) {
                const int row = rbase + v;
                float cam = fmaxf(acc[mi][ni][v] + bias, 0.0f);
                gout[(size_t)row * 4096 + col] = f[(size_t)row * 4096 + col] - cam;
            }
        }
    }
}

// ---------------------------------------------------------------------------
// h1 = relu(dist @ W1b^T + b1), triangle rows, dist from fp32 g on the fly.
// BM=128, BN=256, BK=64, 256 thr (2x2 waves, wave tile 64x128).
// A staging: thread -> row (t>>3)+32p, 16B chunk (t&7); 8 beats/inst.
// As padded LD=72 u16: store banks ~2-way, frag-read banks 2-way (free).
// ---------------------------------------------------------------------------
#define ALD 72
__global__ __launch_bounds__(256, 2)
void k_dist_l1(const float* __restrict__ g, const u16* __restrict__ W1b,
               const float* __restrict__ b1, u16* __restrict__ h1, int row0)
{
    __shared__ __align__(16) u16 As[128 * ALD];  // 18 KB
    __shared__ __align__(16) u16 Bs[256 * 64];   // 32 KB
    const int t = threadIdx.x, l = t & 63, w = t >> 6;
    const int mloc0 = blockIdx.x * 128;
    const int n0 = blockIdx.y * 256;

    // prologue: decode 4 row-pairs, build pointers (hot loop = loads only)
    const float* gip[4]; const float* gjp[4]; u16* dstp[4];
#pragma unroll
    for (int p = 0; p < 4; ++p) {
        const int rl = (t >> 3) + 32 * p;
        int pi, pj; tri_decode(row0 + mloc0 + rl, pi, pj);
        gip[p] = g + (size_t)pi * 4096 + (t & 7) * 4;
        gjp[p] = g + (size_t)pj * 4096 + (t & 7) * 4;
        dstp[p] = &As[rl * ALD + (t & 7) * 4];
    }
    const u16* Wb = W1b + (size_t)(n0 + w * 64 + (l >> 3)) * 4096 + (l & 7) * 8;

    f32x4 acc[4][8] = {};
    const int wr = (w >> 1) * 64, wc = (w & 1) * 128;
    const int lrow = l & 15, lk = (l >> 4) * 8;

    for (int k0 = 0; k0 < 4096; k0 += 64) {
        __syncthreads();
#pragma unroll
        for (int q = 0; q < 8; ++q)
            gll16(&Bs[(w * 64 + q * 8) * 64], Wb + (size_t)q * 8 * 4096 + k0);
#pragma unroll
        for (int p = 0; p < 4; ++p) {
            f32x4 i0 = *(const f32x4*)(gip[p] + k0);
            f32x4 i1 = *(const f32x4*)(gip[p] + k0 + 32);
            f32x4 j0 = *(const f32x4*)(gjp[p] + k0);
            f32x4 j1 = *(const f32x4*)(gjp[p] + k0 + 32);
            uint2 lo = make_uint2(pkbf(fabsf(j0.x - i0.x), fabsf(j0.y - i0.y)),
                                  pkbf(fabsf(j0.z - i0.z), fabsf(j0.w - i0.w)));
            uint2 hi = make_uint2(pkbf(fabsf(j1.x - i1.x), fabsf(j1.y - i1.y)),
                                  pkbf(fabsf(j1.z - i1.z), fabsf(j1.w - i1.w)));
            *reinterpret_cast<uint2*>(dstp[p])      = lo;   // k [4c,4c+4)
            *reinterpret_cast<uint2*>(dstp[p] + 32) = hi;   // k [32+4c,..)
        }
        __syncthreads();
#pragma unroll
        for (int kk = 0; kk < 64; kk += 32) {
            bf16x8 af[4], bfr[8];
#pragma unroll
            for (int mi = 0; mi < 4; ++mi)
                af[mi] = *(const bf16x8*)&As[(wr + mi * 16 + lrow) * ALD + kk + lk];
#pragma unroll
            for (int ni = 0; ni < 8; ++ni)
                bfr[ni] = *(const bf16x8*)&Bs[(wc + ni * 16 + lrow) * 64 + kk + lk];
#pragma unroll
            for (int mi = 0; mi < 4; ++mi)
#pragma unroll
                for (int ni = 0; ni < 8; ++ni)
                    acc[mi][ni] = MFMA16(af[mi], bfr[ni], acc[mi][ni]);
        }
    }
    const int rq = (l >> 4) * 4;
#pragma unroll
    for (int ni = 0; ni < 8; ++ni) {
        const int col = n0 + wc + ni * 16 + lrow;
        const float bias = b1[col];
#pragma unroll
        for (int mi = 0; mi < 4; ++mi) {
            const int rbase = mloc0 + wr + mi * 16 + rq;
#pragma unroll
            for (int v = 0; v < 4; ++v) {
                float x = fmaxf(acc[mi][ni][v] + bias, 0.0f);
                h1[(size_t)(rbase + v) * 2048 + col] = (u16)(pkbf(x, 0.0f) & 0xFFFF);
            }
        }
    }
}

// ---------------------------------------------------------------------------
// C = relu(A @ B^T + bias), bf16 A/B/C, fp32 bias. BM=BN=128, BK=64.
// ---------------------------------------------------------------------------
__global__ __launch_bounds__(256, 2)
void k_gemm_relu(const u16* __restrict__ A, const u16* __restrict__ B,
                 const float* __restrict__ bias, u16* __restrict__ C,
                 int N, int K)
{
    __shared__ __align__(16) u16 As[128 * 64];
    __shared__ __align__(16) u16 Bs[128 * 64];
    const int t = threadIdx.x, l = t & 63, w = t >> 6;
    const int m0 = blockIdx.x * 128, n0 = blockIdx.y * 128;
    const u16* Ab = A + (size_t)(m0 + w * 32 + (l >> 3)) * K + (l & 7) * 8;
    const u16* Bb = B + (size_t)(n0 + w * 32 + (l >> 3)) * K + (l & 7) * 8;
    f32x4 acc[4][4] = {};
    const int wr = (w >> 1) * 64, wc = (w & 1) * 64;
    const int lrow = l & 15, lk = (l >> 4) * 8;

    for (int k0 = 0; k0 < K; k0 += 64) {
        __syncthreads();
#pragma unroll
        for (int q = 0; q < 4; ++q) {
            gll16(&As[(w * 32 + q * 8) * 64], Ab + (size_t)q * 8 * K + k0);
            gll16(&Bs[(w * 32 + q * 8) * 64], Bb + (size_t)q * 8 * K + k0);
        }
        __syncthreads();
#pragma unroll
        for (int kk = 0; kk < 64; kk += 32) {
            bf16x8 af[4], bfr[4];
#pragma unroll
            for (int mi = 0; mi < 4; ++mi)
                af[mi] = *(const bf16x8*)&As[(wr + mi * 16 + lrow) * 64 + kk + lk];
#pragma unroll
            for (int ni = 0; ni < 4; ++ni)
                bfr[ni] = *(const bf16x8*)&Bs[(wc + ni * 16 + lrow) * 64 + kk + lk];
#pragma unroll
            for (int mi = 0; mi < 4; ++mi)
#pragma unroll
                for (int ni = 0; ni < 4; ++ni)
                    acc[mi][ni] = MFMA16(af[mi], bfr[ni], acc[mi][ni]);
        }
    }
    const int rq = (l >> 4) * 4;
#pragma unroll
    for (int ni = 0; ni < 4; ++ni) {
        const int col = n0 + wc + ni * 16 + lrow;
        const float bv = bias[col];
#pragma unroll
        for (int mi = 0; mi < 4; ++mi) {
            const int rbase = m0 + wr + mi * 16 + rq;
#pragma unroll
            for (int v = 0; v < 4; ++v) {
                float x = fmaxf(acc[mi][ni][v] + bv, 0.0f);
                C[(size_t)(rbase + v) * N + col] = (u16)(pkbf(x, 0.0f) & 0xFFFF);
            }
        }
    }
}

// ---------------------------------------------------------------------------
// out[i,j] = out[j,i] = sigmoid(h3[r,:512] . Ws + bs). One wave per tri-row.
// ---------------------------------------------------------------------------
__global__ __launch_bounds__(256)
void k_head(const u16* __restrict__ h3, const float* __restrict__ Wsv,
            const float* __restrict__ bsv, float* __restrict__ out, int row0)
{
    const int t = threadIdx.x, l = t & 63, wv = t >> 6;
    const int rl = blockIdx.x * 4 + wv;
    if (row0 + rl >= TRI) return;
    const u16x8 hv = *(const u16x8*)(h3 + (size_t)rl * 512 + l * 8);
    const f32x4 w0 = ((const f32x4*)Wsv)[l * 2];
    const f32x4 w1 = ((const f32x4*)Wsv)[l * 2 + 1];
    float hs[8];
#pragma unroll
    for (int e = 0; e < 8; ++e) {
        union { unsigned int i; float f; } v;
        v.i = ((unsigned int)hv[e]) << 16;
        hs[e] = v.f;
    }
    float s = hs[0] * w0.x + hs[1] * w0.y + hs[2] * w0.z + hs[3] * w0.w
            + hs[4] * w1.x + hs[5] * w1.y + hs[6] * w1.z + hs[7] * w1.w;
#pragma unroll
    for (int off = 32; off >= 1; off >>= 1) s += __shfl_down(s, off, 64);
    if (l == 0) {
        float v = 1.0f / (1.0f + __expf(-(s + bsv[0])));
        int pi, pj; tri_decode(row0 + rl, pi, pj);
        out[pi * NTRK + pj] = v;
        out[pj * NTRK + pi] = v;
    }
}

// ---------------------------------------------------------------------------
extern "C" void kernel_launch(void* const* d_in, const int* in_sizes, int n_in,
                              void* d_out, int out_size, void* d_ws, size_t ws_size,
                              hipStream_t stream)
{
    const float* f   = (const float*)d_in[0];
    const float* Wc1 = (const float*)d_in[1];
    const float* bc1 = (const float*)d_in[2];
    const float* W1  = (const float*)d_in[3];
    const float* b1  = (const float*)d_in[4];
    const float* W2  = (const float*)d_in[5];
    const float* b2  = (const float*)d_in[6];
    const float* W3  = (const float*)d_in[7];
    const float* b3  = (const float*)d_in[8];
    const float* Wsv = (const float*)d_in[9];
    const float* bsv = (const float*)d_in[10];
    float* out = (float*)d_out;

    char* wsb = (char*)d_ws;
    size_t off = 0;
    u16* Wc1b = (u16*)(wsb + off); off += (size_t)4096 * 4096 * 2;
    u16* W1b  = (u16*)(wsb + off); off += (size_t)2048 * 4096 * 2;
    u16* W2b  = (u16*)(wsb + off); off += (size_t)1024 * 2048 * 2;
    u16* W3b  = (u16*)(wsb + off); off += (size_t)512  * 1024 * 2;
    u16* fb   = (u16*)(wsb + off); off += (size_t)192  * 4096 * 2;
    float* g  = (float*)(wsb + off); off += (size_t)192 * 4096 * 4;
    const size_t fixed = off;

    // chunk rows (mult of 128); prefer whole padded triangle in one pass
    const int Rcand[6] = {18688, 9344, 4736, 2432, 1280, 384};
    int R = 128;
    for (int c = 0; c < 6; ++c) {
        size_t need = fixed + (size_t)Rcand[c] * (2048 + 1024 + 512) * 2;
        if (need <= ws_size) { R = Rcand[c]; break; }
    }
    u16* h1 = (u16*)(wsb + fixed);
    u16* h2 = h1 + (size_t)R * 2048;
    u16* h3 = h2 + (size_t)R * 1024;

    k_cvt<<<512, 256, 0, stream>>>(Wc1, Wc1b, 4096 * 4096 / 4);
    k_cvt<<<512, 256, 0, stream>>>(W1,  W1b,  2048 * 4096 / 4);
    k_cvt<<<256, 256, 0, stream>>>(W2,  W2b,  1024 * 2048 / 4);
    k_cvt<<<128, 256, 0, stream>>>(W3,  W3b,  512  * 1024 / 4);
    k_cvt<<<128, 256, 0, stream>>>(f,   fb,   192  * 4096 / 4);

    k_cam<<<dim3(3, 32), 256, 0, stream>>>(fb, Wc1b, bc1, f, g);

    for (int r0 = 0; r0 < TRI; r0 += R) {
        int rows = TRIP - r0; if (rows > R) rows = R;   // mult of 128
        k_dist_l1<<<dim3(rows / 128, 8), 256, 0, stream>>>(g, W1b, b1, h1, r0);
        k_gemm_relu<<<dim3(rows / 128, 8), 256, 0, stream>>>(h1, W2b, b2, h2, 1024, 2048);
        k_gemm_relu<<<dim3(rows / 128, 4), 256, 0, stream>>>(h2, W3b, b3, h3, 512, 1024);
        k_head<<<dim3(rows / 4), 256, 0, stream>>>(h3, Wsv, bsv, out, r0);
    }
}